// Round 8
// baseline (219.976 us; speedup 1.0000x reference)
//
#include <hip/hip_runtime.h>
#include <hip/hip_bf16.h>
#include <stdint.h>

typedef unsigned short u16;
typedef unsigned int   u32;
typedef unsigned long long u64;
typedef __bf16 bf16x8 __attribute__((ext_vector_type(8)));
typedef float  f32x4  __attribute__((ext_vector_type(4)));
typedef short  s16x4  __attribute__((ext_vector_type(4)));

#define D_MODEL 1024
#define NH 16
#define DHEAD 64
#define BB 4
#define SS 2048
#define MM (BB*SS)   // 8192 rows

__device__ __forceinline__ u16 f2bf(float f) {
    unsigned int u = __float_as_uint(f);
    u += 0x7fffu + ((u >> 16) & 1u);   // RNE
    return (u16)(u >> 16);
}
__device__ __forceinline__ float bf2f(u16 s) {
    return __uint_as_float(((unsigned int)s) << 16);
}
__device__ __forceinline__ u32 pkbf(float a, float b) {  // v_cvt_pk_bf16_f32 (RNE)
    __hip_bfloat162 h = __float22bfloat162_rn(make_float2(a, b));
    return *(u32*)&h;
}

union U8 {
    uint4 q;
    u16   v[8];
    bf16x8 f;
};
union B8 { u32 w[4]; bf16x8 f; };
union V8 { s16x4 h[2]; bf16x8 f; };

// ---------------------------------------------------------------- merged cvt f32->bf16 (x, w_qkv, w_out)
#define N4X (MM * D_MODEL / 4)        // 2097152
#define N4W (D_MODEL * D_MODEL / 4)   // 262144
__global__ __launch_bounds__(256) void cvt_all_kernel(const float* __restrict__ x,
                                                      const float* __restrict__ wq,
                                                      const float* __restrict__ wo,
                                                      u16* __restrict__ xb,
                                                      u16* __restrict__ wqb,
                                                      u16* __restrict__ wob) {
    int i = blockIdx.x * 256 + threadIdx.x;
    const float* s; u16* d; int off;
    if (i < N4X)            { s = x;  d = xb;  off = i; }
    else if (i < N4X + N4W) { s = wq; d = wqb; off = i - N4X; }
    else                    { s = wo; d = wob; off = i - N4X - N4W; }
    float4 f = ((const float4*)s)[off];
    u32 o[2] = { pkbf(f.x, f.y), pkbf(f.z, f.w) };
    ((uint2*)d)[off] = *(const uint2*)o;
}

// ================================================================ GEMM core (BK=64, XOR-swizzled LDS)
template <bool PERMUTE_OUT>
__device__ __forceinline__ void gemm_body(const u16* __restrict__ A,
                                          const u16* __restrict__ Bt,
                                          const float* __restrict__ Bo,
                                          u16* __restrict__ Cq, u16* __restrict__ CqT,
                                          float* __restrict__ Out)
{
    __shared__ __align__(16) u16 As[128*64];
    __shared__ __align__(16) u16 Bs[128*64];

    const int tid  = threadIdx.x;
    const int wave = tid >> 6;
    const int lane = tid & 63;
    const int quad = lane >> 4;
    const int l16  = lane & 15;
    // XCD-chunked swizzle (bijective, grid 512 = 8 XCD * 64): blocks sharing bm co-locate on an XCD
    const int dsw = blockIdx.x;
    const int sl  = dsw >> 3;
    const int bm  = ((sl >> 3) << 3) + (dsw & 7);
    const int bn  = sl & 7;
    const int wm = wave >> 1, wn = wave & 1;

    f32x4 acc[4][4] = {};

    const int rp = tid >> 3;              // row in 32-row pass
    const int ch = tid & 7;               // physical chunk (8 elems)
    const int sc = ch ^ (rp & 7);         // source (logical) chunk

    const u16* Ab = A  + (size_t)(bm * 128 + rp) * D_MODEL + sc * 8;
    const u16* Bb = Bt + (size_t)(bn * 128 + rp) * D_MODEL + sc * 8;
    const int xr = l16 & 7;

    for (int k0 = 0; k0 < D_MODEL; k0 += 64) {
#pragma unroll
        for (int p = 0; p < 4; ++p) {
            __builtin_amdgcn_global_load_lds(
                (__attribute__((address_space(1))) void*)(Ab + (size_t)(32*p) * D_MODEL + k0),
                (__attribute__((address_space(3))) void*)(As + p*2048 + tid*8), 16, 0, 0);
            __builtin_amdgcn_global_load_lds(
                (__attribute__((address_space(1))) void*)(Bb + (size_t)(32*p) * D_MODEL + k0),
                (__attribute__((address_space(3))) void*)(Bs + p*2048 + tid*8), 16, 0, 0);
        }
        __syncthreads();

#pragma unroll
        for (int ks = 0; ks < 2; ++ks) {
            bf16x8 af[4], bfr[4];
#pragma unroll
            for (int t = 0; t < 4; ++t)
                af[t] = *(const bf16x8*)(const void*)(
                    As + (wm*64 + t*16 + l16)*64 + (((ks*4 + quad) ^ xr) * 8));
#pragma unroll
            for (int t = 0; t < 4; ++t)
                bfr[t] = *(const bf16x8*)(const void*)(
                    Bs + (wn*64 + t*16 + l16)*64 + (((ks*4 + quad) ^ xr) * 8));
#pragma unroll
            for (int i = 0; i < 4; ++i)
#pragma unroll
                for (int j = 0; j < 4; ++j)
                    acc[i][j] = __builtin_amdgcn_mfma_f32_16x16x32_bf16(af[i], bfr[j], acc[i][j], 0, 0, 0);
        }
        __syncthreads();
    }

    const int rowbase = bm*128 + wm*64;
    const int colbase = bn*128 + wn*64;
    if (PERMUTE_OUT) {
#pragma unroll
        for (int j = 0; j < 4; ++j) {
            const int col = colbase + j*16 + l16;
            const int h = col >> 6, dh = col & 63;
#pragma unroll
            for (int i = 0; i < 4; ++i) {
                const int row0 = rowbase + i*16 + quad*4;
                const int b = row0 >> 11, s0 = row0 & (SS - 1);
#pragma unroll
                for (int r = 0; r < 4; ++r)
                    Cq[(((size_t)(b*NH + h))*SS + s0 + r)*DHEAD + dh] = f2bf(acc[i][j][r]);
                u64 w = (u64)pkbf(acc[i][j][0], acc[i][j][1])
                      | ((u64)pkbf(acc[i][j][2], acc[i][j][3]) << 32);
                *(u64*)(CqT + ((size_t)((b*NH + h)*DHEAD + dh))*SS + s0) = w;
            }
        }
    } else {
#pragma unroll
        for (int j = 0; j < 4; ++j) {
            const int col = colbase + j*16 + l16;
            const float bias = Bo[col];
#pragma unroll
            for (int i = 0; i < 4; ++i) {
#pragma unroll
                for (int r = 0; r < 4; ++r) {
                    const int row = rowbase + i*16 + quad*4 + r;
                    Out[(size_t)row * D_MODEL + col] = acc[i][j][r] + bias;
                }
            }
        }
    }
}

__global__ __launch_bounds__(256) void gemm_qkv_kernel(const u16* __restrict__ A,
                                                       const u16* __restrict__ Bt,
                                                       u16* __restrict__ Cq,
                                                       u16* __restrict__ CqT) {
    gemm_body<true>(A, Bt, nullptr, Cq, CqT, nullptr);
}

__global__ __launch_bounds__(256) void gemm_out_kernel(const u16* __restrict__ A,
                                                       const u16* __restrict__ Bt,
                                                       const float* __restrict__ Bo,
                                                       float* __restrict__ Out) {
    gemm_body<false>(A, Bt, Bo, nullptr, nullptr, Out);
}

// ---------------------------------------------------------------- attention (Q=K=V), S^T formulation
// Software-pipelined (1 tile deep) on top of r7's counted-vmcnt scheme, 4 LDS buffers:
//   iter kt: barrier/wait -> issue DMA(kt+3) -> QK(kt+1)->s [MFMA] -> PV(kt) w/ pb_prev [MFMA,
//   independent of s] -> softmax(s)->pb [VALU, interleaves with PV MFMAs].
// This breaks the QK->softmax->PV serial phase chain: the MFMA pipe chews QK(kt+1)+PV(kt)
// back-to-back while the VALU does softmax in the gaps. Only pb (16 VGPR) crosses iterations.
// Buffer safety (4 bufs): iter kt touches LDS tiles kt (V) and kt+1 (K); DMA kt+3 writes
// buf[(kt+3)&3] = buf[(kt-1)&3], last read at iter kt-1, complete before this barrier.
// All fragment offsets / permuted-key PV / ones-MFMA lsum identical to r4 (proven).
__global__ __launch_bounds__(256, 2) void attn_kernel(const u16* __restrict__ qkv,   // [B*H][2048][64]
                                                      const u16* __restrict__ qkvT,  // [B*H][64][2048]
                                                      u16* __restrict__ outb)        // [B][S][1024]
{
    __shared__ __align__(16) u16 Ks[4*2048];    // 4 buf x [32 key][64 dh] chunk-swizzled
    __shared__ __align__(16) u16 Vt[4*2048];    // 4 buf x [64 dh][32 key] chunk-swizzled

    const int tid  = threadIdx.x;
    const int wave = tid >> 6;
    const int lane = tid & 63;
    const int quad = lane >> 4;
    const int l16  = lane & 15;

    // XCD-chunked swizzle (bijective, grid 512 = 8 XCD * 64): 8 q-blocks of one bh share an XCD L2
    const int dsw  = blockIdx.x;
    const int sl   = dsw >> 3;
    const int bh   = ((sl >> 3) << 3) + (dsw & 7);
    const int qblk = sl & 7;
    const int b = bh >> 4, h = bh & 15;
    const int qbase = qblk * 256 + wave * 64;

    const u16* Qp = qkv + (size_t)bh * SS * DHEAD;
    const float qscale = 0.125f * 1.4426950408889634f;  // 1/sqrt(64) * log2(e)

    // Q as B-operand frags (16x16x32): B[k=dh][n=q], lane reads 8 consecutive dh at fixed q
    bf16x8 qb[4][2];
#pragma unroll
    for (int nt = 0; nt < 4; ++nt)
#pragma unroll
        for (int ks = 0; ks < 2; ++ks) {
            U8 raw; raw.q = *(const uint4*)(Qp + (size_t)(qbase + nt*16 + l16)*DHEAD + ks*32 + quad*8);
            U8 w;
#pragma unroll
            for (int jj = 0; jj < 4; ++jj)
                ((u32*)&w)[jj] = pkbf(bf2f(raw.v[2*jj]) * qscale, bf2f(raw.v[2*jj+1]) * qscale);
            qb[nt][ks] = w.f;
        }

    // DMA staging sources (chunk-swizzled so frag reads are conflict-free)
    const int rK = tid >> 3, cK = (tid & 7) ^ ((rK >> 1) & 7);
    const u16* srcK = qkv  + (size_t)bh * SS * DHEAD + rK * DHEAD + cK * 8;
    const int rV = tid >> 2, cV = (tid & 3) ^ ((rV >> 1) & 3);
    const u16* srcV = qkvT + (size_t)bh * DHEAD * SS + (size_t)rV * SS + cV * 8;

    // frag read offsets (r0-verified)
    const int h8 = (l16 >> 1) & 7, h4 = (l16 >> 1) & 3;
    const int ko0 = l16*64 + ((quad)     ^ h8) * 8;   // K frag, ks=0
    const int ko1 = l16*64 + ((4 + quad) ^ h8) * 8;   // K frag, ks=1
    const int vo0 = l16*32 + (((quad >> 1))     ^ h4) * 8 + (quad & 1) * 4;   // V keys 4q..4q+3
    const int vo1 = l16*32 + ((2 + (quad >> 1)) ^ h4) * 8 + (quad & 1) * 4;   // V keys 16+4q..+3

    bf16x8 ones;
#pragma unroll
    for (int j = 0; j < 8; ++j) ones[j] = (__bf16)1.0f;

    f32x4 ot[4][4] = {};    // O^T[dh-tile][q-tile]
    f32x4 lsum[4]  = {};
    B8 pb[4];               // packed P for the tile about to enter PV (loop-carried)

    auto issue = [&](int t) {
        __builtin_amdgcn_global_load_lds(
            (__attribute__((address_space(1))) void*)(srcK + (size_t)t*32*DHEAD),
            (__attribute__((address_space(3))) void*)(Ks + (t&3)*2048 + tid*8), 16, 0, 0);
        __builtin_amdgcn_global_load_lds(
            (__attribute__((address_space(1))) void*)(srcV + t*32),
            (__attribute__((address_space(3))) void*)(Vt + (t&3)*2048 + tid*8), 16, 0, 0);
    };

    // prologue: issue tiles 0..2; QK(0)+softmax(0) -> pb
    issue(0); issue(1); issue(2);
    asm volatile("s_waitcnt vmcnt(4) lgkmcnt(0)\n\ts_barrier" ::: "memory");
    {
        const u16* Kb = Ks;
        f32x4 s[2][4];
#pragma unroll
        for (int mt = 0; mt < 2; ++mt) {
            bf16x8 kf0 = *(const bf16x8*)(const void*)(Kb + mt*1024 + ko0);
            bf16x8 kf1 = *(const bf16x8*)(const void*)(Kb + mt*1024 + ko1);
#pragma unroll
            for (int nt = 0; nt < 4; ++nt) {
                f32x4 z = {};
                z = __builtin_amdgcn_mfma_f32_16x16x32_bf16(kf0, qb[nt][0], z, 0, 0, 0);
                s[mt][nt] = __builtin_amdgcn_mfma_f32_16x16x32_bf16(kf1, qb[nt][1], z, 0, 0, 0);
            }
        }
#pragma unroll
        for (int nt = 0; nt < 4; ++nt) {
#pragma unroll
            for (int mt = 0; mt < 2; ++mt) {
                float p0 = __builtin_amdgcn_exp2f(s[mt][nt][0]);
                float p1 = __builtin_amdgcn_exp2f(s[mt][nt][1]);
                float p2 = __builtin_amdgcn_exp2f(s[mt][nt][2]);
                float p3 = __builtin_amdgcn_exp2f(s[mt][nt][3]);
                pb[nt].w[2*mt]   = pkbf(p0, p1);
                pb[nt].w[2*mt+1] = pkbf(p2, p3);
            }
        }
    }

    // steady loop: iter kt computes QK(kt+1), PV(kt), softmax(kt+1)
    for (int kt = 0; kt < SS/32 - 1; ++kt) {
        if (kt < SS/32 - 3) {
            asm volatile("s_waitcnt vmcnt(2) lgkmcnt(0)\n\ts_barrier" ::: "memory");
            issue(kt + 3);
        } else if (kt == SS/32 - 3) {
            asm volatile("s_waitcnt vmcnt(2) lgkmcnt(0)\n\ts_barrier" ::: "memory");
        } else {
            asm volatile("s_waitcnt vmcnt(0) lgkmcnt(0)\n\ts_barrier" ::: "memory");
        }
        const u16* Kb = Ks + ((kt+1)&3)*2048;   // K tile kt+1 (QK)
        const u16* Vb = Vt + (kt&3)*2048;       // V tile kt   (PV)

        // LDS reads up front: V frags (tile kt) + K frags (tile kt+1)
        V8 vt[4];
#pragma unroll
        for (int dt = 0; dt < 4; ++dt) {
            vt[dt].h[0] = *(const s16x4*)(const void*)(Vb + dt*512 + vo0);
            vt[dt].h[1] = *(const s16x4*)(const void*)(Vb + dt*512 + vo1);
        }
        bf16x8 kf[2][2];
#pragma unroll
        for (int mt = 0; mt < 2; ++mt) {
            kf[mt][0] = *(const bf16x8*)(const void*)(Kb + mt*1024 + ko0);
            kf[mt][1] = *(const bf16x8*)(const void*)(Kb + mt*1024 + ko1);
        }

        // QK(kt+1) -> s
        f32x4 s[2][4];
        __builtin_amdgcn_s_setprio(1);
#pragma unroll
        for (int mt = 0; mt < 2; ++mt)
#pragma unroll
            for (int nt = 0; nt < 4; ++nt) {
                f32x4 z = {};
                z = __builtin_amdgcn_mfma_f32_16x16x32_bf16(kf[mt][0], qb[nt][0], z, 0, 0, 0);
                s[mt][nt] = __builtin_amdgcn_mfma_f32_16x16x32_bf16(kf[mt][1], qb[nt][1], z, 0, 0, 0);
            }

        // PV(kt) with pb from previous iteration (independent of s -> softmax overlaps)
#pragma unroll
        for (int nt = 0; nt < 4; ++nt)
            lsum[nt] = __builtin_amdgcn_mfma_f32_16x16x32_bf16(ones, pb[nt].f, lsum[nt], 0, 0, 0);
#pragma unroll
        for (int dt = 0; dt < 4; ++dt)
#pragma unroll
            for (int nt = 0; nt < 4; ++nt)
                ot[dt][nt] = __builtin_amdgcn_mfma_f32_16x16x32_bf16(vt[dt].f, pb[nt].f, ot[dt][nt], 0, 0, 0);
        __builtin_amdgcn_s_setprio(0);

        // softmax(kt+1): s -> pb (VALU; fills MFMA issue gaps)
#pragma unroll
        for (int nt = 0; nt < 4; ++nt) {
#pragma unroll
            for (int mt = 0; mt < 2; ++mt) {
                float p0 = __builtin_amdgcn_exp2f(s[mt][nt][0]);
                float p1 = __builtin_amdgcn_exp2f(s[mt][nt][1]);
                float p2 = __builtin_amdgcn_exp2f(s[mt][nt][2]);
                float p3 = __builtin_amdgcn_exp2f(s[mt][nt][3]);
                pb[nt].w[2*mt]   = pkbf(p0, p1);
                pb[nt].w[2*mt+1] = pkbf(p2, p3);
            }
        }
    }

    // epilogue tile 63: PV only (tile 63 data waited by the kt=62 vmcnt(0))
    {
        const u16* Vb = Vt + ((SS/32 - 1)&3)*2048;
        V8 vt[4];
#pragma unroll
        for (int dt = 0; dt < 4; ++dt) {
            vt[dt].h[0] = *(const s16x4*)(const void*)(Vb + dt*512 + vo0);
            vt[dt].h[1] = *(const s16x4*)(const void*)(Vb + dt*512 + vo1);
        }
        __builtin_amdgcn_s_setprio(1);
#pragma unroll
        for (int nt = 0; nt < 4; ++nt)
            lsum[nt] = __builtin_amdgcn_mfma_f32_16x16x32_bf16(ones, pb[nt].f, lsum[nt], 0, 0, 0);
#pragma unroll
        for (int dt = 0; dt < 4; ++dt)
#pragma unroll
            for (int nt = 0; nt < 4; ++nt)
                ot[dt][nt] = __builtin_amdgcn_mfma_f32_16x16x32_bf16(vt[dt].f, pb[nt].f, ot[dt][nt], 0, 0, 0);
        __builtin_amdgcn_s_setprio(0);
    }

    // epilogue: O = O^T / lsum (lsum complete per lane), packed 8B stores
    float inv[4];
#pragma unroll
    for (int nt = 0; nt < 4; ++nt) inv[nt] = 1.0f / lsum[nt][0];
#pragma unroll
    for (int dt = 0; dt < 4; ++dt)
#pragma unroll
        for (int nt = 0; nt < 4; ++nt) {
            u64 w = (u64)pkbf(ot[dt][nt][0]*inv[nt], ot[dt][nt][1]*inv[nt])
                  | ((u64)pkbf(ot[dt][nt][2]*inv[nt], ot[dt][nt][3]*inv[nt]) << 32);
            *(u64*)(outb + ((size_t)(b*SS + qbase + nt*16 + l16))*D_MODEL
                         + h*64 + dt*16 + quad*4) = w;
        }
}

// ---------------------------------------------------------------- launcher
extern "C" void kernel_launch(void* const* d_in, const int* in_sizes, int n_in,
                              void* d_out, int out_size, void* d_ws, size_t ws_size,
                              hipStream_t stream)
{
    (void)in_sizes; (void)n_in; (void)out_size; (void)ws_size;
    const float* x  = (const float*)d_in[0];
    const float* wq = (const float*)d_in[1];
    const float* wo = (const float*)d_in[2];
    const float* bo = (const float*)d_in[3];

    char* ws = (char*)d_ws;
    u16* xb    = (u16*)(ws);                          // 16 MiB  [8192][1024] bf16 x
    u16* wqb   = (u16*)(ws + (size_t)(16 << 20));     //  2 MiB
    u16* wob   = (u16*)(ws + (size_t)(18 << 20));     //  2 MiB
    u16* qkvb  = (u16*)(ws + (size_t)(20 << 20));     // 16 MiB  [64][2048][64]
    u16* qkvTb = (u16*)(ws + (size_t)(36 << 20));     // 16 MiB  [64][64][2048]
    u16* attb  = xb;                                  // reuse x-bf16 buffer for attention output

    cvt_all_kernel<<<(N4X + 2*N4W) / 256, 256, 0, stream>>>(x, wq, wo, xb, wqb, wob);
    gemm_qkv_kernel<<<(MM/128) * (D_MODEL/128), 256, 0, stream>>>(xb, wqb, qkvb, qkvTb);
    attn_kernel<<<BB * NH * (SS/256), 256, 0, stream>>>(qkvb, qkvTb, attb);
    gemm_out_kernel<<<(MM/128) * (D_MODEL/128), 256, 0, stream>>>(attb, wob, bo, (float*)d_out);
}

// Round 9
// 219.538 us; speedup vs baseline: 1.0020x; 1.0020x over previous
//
#include <hip/hip_runtime.h>
#include <hip/hip_bf16.h>
#include <stdint.h>

typedef unsigned short u16;
typedef unsigned int   u32;
typedef unsigned long long u64;
typedef __bf16 bf16x8 __attribute__((ext_vector_type(8)));
typedef float  f32x4  __attribute__((ext_vector_type(4)));
typedef short  s16x4  __attribute__((ext_vector_type(4)));

#define D_MODEL 1024
#define NH 16
#define DHEAD 64
#define BB 4
#define SS 2048
#define MM (BB*SS)   // 8192 rows

__device__ __forceinline__ u16 f2bf(float f) {
    unsigned int u = __float_as_uint(f);
    u += 0x7fffu + ((u >> 16) & 1u);   // RNE
    return (u16)(u >> 16);
}
__device__ __forceinline__ float bf2f(u16 s) {
    return __uint_as_float(((unsigned int)s) << 16);
}
__device__ __forceinline__ u32 pkbf(float a, float b) {  // v_cvt_pk_bf16_f32 (RNE)
    __hip_bfloat162 h = __float22bfloat162_rn(make_float2(a, b));
    return *(u32*)&h;
}

union U8 {
    uint4 q;
    u16   v[8];
    bf16x8 f;
};
union B8 { u32 w[4]; bf16x8 f; };
union V8 { s16x4 h[2]; bf16x8 f; };

// ---------------------------------------------------------------- merged cvt f32->bf16 (x, w_qkv, w_out)
#define N4X (MM * D_MODEL / 4)        // 2097152
#define N4W (D_MODEL * D_MODEL / 4)   // 262144
__global__ __launch_bounds__(256) void cvt_all_kernel(const float* __restrict__ x,
                                                      const float* __restrict__ wq,
                                                      const float* __restrict__ wo,
                                                      u16* __restrict__ xb,
                                                      u16* __restrict__ wqb,
                                                      u16* __restrict__ wob) {
    int i = blockIdx.x * 256 + threadIdx.x;
    const float* s; u16* d; int off;
    if (i < N4X)            { s = x;  d = xb;  off = i; }
    else if (i < N4X + N4W) { s = wq; d = wqb; off = i - N4X; }
    else                    { s = wo; d = wob; off = i - N4X - N4W; }
    float4 f = ((const float4*)s)[off];
    u32 o[2] = { pkbf(f.x, f.y), pkbf(f.z, f.w) };
    ((uint2*)d)[off] = *(const uint2*)o;
}

// ================================================================ GEMM core (BK=64, XOR-swizzled LDS)
template <bool PERMUTE_OUT>
__device__ __forceinline__ void gemm_body(const u16* __restrict__ A,
                                          const u16* __restrict__ Bt,
                                          const float* __restrict__ Bo,
                                          u16* __restrict__ Cq, u16* __restrict__ CqT,
                                          float* __restrict__ Out)
{
    __shared__ __align__(16) u16 As[128*64];
    __shared__ __align__(16) u16 Bs[128*64];

    const int tid  = threadIdx.x;
    const int wave = tid >> 6;
    const int lane = tid & 63;
    const int quad = lane >> 4;
    const int l16  = lane & 15;
    // XCD-chunked swizzle (bijective, grid 512 = 8 XCD * 64): blocks sharing bm co-locate on an XCD
    const int dsw = blockIdx.x;
    const int sl  = dsw >> 3;
    const int bm  = ((sl >> 3) << 3) + (dsw & 7);
    const int bn  = sl & 7;
    const int wm = wave >> 1, wn = wave & 1;

    f32x4 acc[4][4] = {};

    const int rp = tid >> 3;              // row in 32-row pass
    const int ch = tid & 7;               // physical chunk (8 elems)
    const int sc = ch ^ (rp & 7);         // source (logical) chunk

    const u16* Ab = A  + (size_t)(bm * 128 + rp) * D_MODEL + sc * 8;
    const u16* Bb = Bt + (size_t)(bn * 128 + rp) * D_MODEL + sc * 8;
    const int xr = l16 & 7;

    for (int k0 = 0; k0 < D_MODEL; k0 += 64) {
#pragma unroll
        for (int p = 0; p < 4; ++p) {
            __builtin_amdgcn_global_load_lds(
                (__attribute__((address_space(1))) void*)(Ab + (size_t)(32*p) * D_MODEL + k0),
                (__attribute__((address_space(3))) void*)(As + p*2048 + tid*8), 16, 0, 0);
            __builtin_amdgcn_global_load_lds(
                (__attribute__((address_space(1))) void*)(Bb + (size_t)(32*p) * D_MODEL + k0),
                (__attribute__((address_space(3))) void*)(Bs + p*2048 + tid*8), 16, 0, 0);
        }
        __syncthreads();

#pragma unroll
        for (int ks = 0; ks < 2; ++ks) {
            bf16x8 af[4], bfr[4];
#pragma unroll
            for (int t = 0; t < 4; ++t)
                af[t] = *(const bf16x8*)(const void*)(
                    As + (wm*64 + t*16 + l16)*64 + (((ks*4 + quad) ^ xr) * 8));
#pragma unroll
            for (int t = 0; t < 4; ++t)
                bfr[t] = *(const bf16x8*)(const void*)(
                    Bs + (wn*64 + t*16 + l16)*64 + (((ks*4 + quad) ^ xr) * 8));
#pragma unroll
            for (int i = 0; i < 4; ++i)
#pragma unroll
                for (int j = 0; j < 4; ++j)
                    acc[i][j] = __builtin_amdgcn_mfma_f32_16x16x32_bf16(af[i], bfr[j], acc[i][j], 0, 0, 0);
        }
        __syncthreads();
    }

    const int rowbase = bm*128 + wm*64;
    const int colbase = bn*128 + wn*64;
    if (PERMUTE_OUT) {
#pragma unroll
        for (int j = 0; j < 4; ++j) {
            const int col = colbase + j*16 + l16;
            const int h = col >> 6, dh = col & 63;
#pragma unroll
            for (int i = 0; i < 4; ++i) {
                const int row0 = rowbase + i*16 + quad*4;
                const int b = row0 >> 11, s0 = row0 & (SS - 1);
#pragma unroll
                for (int r = 0; r < 4; ++r)
                    Cq[(((size_t)(b*NH + h))*SS + s0 + r)*DHEAD + dh] = f2bf(acc[i][j][r]);
                u64 w = (u64)pkbf(acc[i][j][0], acc[i][j][1])
                      | ((u64)pkbf(acc[i][j][2], acc[i][j][3]) << 32);
                *(u64*)(CqT + ((size_t)((b*NH + h)*DHEAD + dh))*SS + s0) = w;
            }
        }
    } else {
#pragma unroll
        for (int j = 0; j < 4; ++j) {
            const int col = colbase + j*16 + l16;
            const float bias = Bo[col];
#pragma unroll
            for (int i = 0; i < 4; ++i) {
#pragma unroll
                for (int r = 0; r < 4; ++r) {
                    const int row = rowbase + i*16 + quad*4 + r;
                    Out[(size_t)row * D_MODEL + col] = acc[i][j][r] + bias;
                }
            }
        }
    }
}

__global__ __launch_bounds__(256) void gemm_qkv_kernel(const u16* __restrict__ A,
                                                       const u16* __restrict__ Bt,
                                                       u16* __restrict__ Cq,
                                                       u16* __restrict__ CqT) {
    gemm_body<true>(A, Bt, nullptr, Cq, CqT, nullptr);
}

__global__ __launch_bounds__(256) void gemm_out_kernel(const u16* __restrict__ A,
                                                       const u16* __restrict__ Bt,
                                                       const float* __restrict__ Bo,
                                                       float* __restrict__ Out) {
    gemm_body<false>(A, Bt, Bo, nullptr, nullptr, Out);
}

// ---------------------------------------------------------------- attention (Q=K=V), S^T formulation
// 32 q per wave (r3's proven geometry/offsets), KVBLK=64 (two proven 32-key sub-bodies per
// barrier), double-buffered 16 KB K+V tiles -> 32 KB LDS/block -> grid 1024 = 4 blocks/CU =
// 16 waves/CU (4/SIMD). Rationale: r7/r8 showed the ~96us wall is unhidden latency at
// 2 waves/SIMD; independent blocks at staggered phases fill each other's stalls (TLP), and
// 32q halves accumulator state so VGPR fits the 4-waves/SIMD 128-reg budget (r6's failure).
// Register-P full-rate PV + ones-MFMA lsum (r4-proven); counted-vmcnt raw barrier (r7-proven).
__global__ __launch_bounds__(256, 4) void attn_kernel(const u16* __restrict__ qkv,   // [B*H][2048][64]
                                                      const u16* __restrict__ qkvT,  // [B*H][64][2048]
                                                      u16* __restrict__ outb)        // [B][S][1024]
{
    __shared__ __align__(16) u16 Ks[2*2*2048];  // [buf][sub][32 key][64 dh] chunk-swizzled
    __shared__ __align__(16) u16 Vt[2*2*2048];  // [buf][sub][64 dh][32 key] chunk-swizzled

    const int tid  = threadIdx.x;
    const int wave = tid >> 6;
    const int lane = tid & 63;
    const int quad = lane >> 4;
    const int l16  = lane & 15;

    // XCD-chunked swizzle (bijective, grid 1024 = 8 XCD * 128): 16 q-blocks of one bh share an XCD L2
    const int dsw  = blockIdx.x;
    const int sl   = dsw >> 3;
    const int bh   = ((sl >> 4) << 3) + (dsw & 7);
    const int qblk = sl & 15;
    const int b = bh >> 4, h = bh & 15;
    const int qbase = qblk * 128 + wave * 32;

    const u16* Qp = qkv + (size_t)bh * SS * DHEAD;
    const float qscale = 0.125f * 1.4426950408889634f;  // 1/sqrt(64) * log2(e)

    // Q as B-operand frags (16x16x32): B[k=dh][n=q], lane reads 8 consecutive dh at fixed q
    bf16x8 qb[2][2];
#pragma unroll
    for (int nt = 0; nt < 2; ++nt)
#pragma unroll
        for (int ks = 0; ks < 2; ++ks) {
            U8 raw; raw.q = *(const uint4*)(Qp + (size_t)(qbase + nt*16 + l16)*DHEAD + ks*32 + quad*8);
            U8 w;
#pragma unroll
            for (int jj = 0; jj < 4; ++jj)
                ((u32*)&w)[jj] = pkbf(bf2f(raw.v[2*jj]) * qscale, bf2f(raw.v[2*jj+1]) * qscale);
            qb[nt][ks] = w.f;
        }

    // DMA staging sources (chunk-swizzled so frag reads are conflict-free)
    const int rK = tid >> 3, cK = (tid & 7) ^ ((rK >> 1) & 7);
    const u16* srcK = qkv  + (size_t)bh * SS * DHEAD + rK * DHEAD + cK * 8;
    const int rV = tid >> 2, cV = (tid & 3) ^ ((rV >> 1) & 3);
    const u16* srcV = qkvT + (size_t)bh * DHEAD * SS + (size_t)rV * SS + cV * 8;

    // frag read offsets (r0-verified)
    const int h8 = (l16 >> 1) & 7, h4 = (l16 >> 1) & 3;
    const int ko0 = l16*64 + ((quad)     ^ h8) * 8;   // K frag, ks=0
    const int ko1 = l16*64 + ((4 + quad) ^ h8) * 8;   // K frag, ks=1
    const int vo0 = l16*32 + (((quad >> 1))     ^ h4) * 8 + (quad & 1) * 4;   // V keys 4q..4q+3
    const int vo1 = l16*32 + ((2 + (quad >> 1)) ^ h4) * 8 + (quad & 1) * 4;   // V keys 16+4q..+3

    bf16x8 ones;
#pragma unroll
    for (int j = 0; j < 8; ++j) ones[j] = (__bf16)1.0f;

    f32x4 ot[4][2] = {};    // O^T[dh-tile][q-tile]
    f32x4 lsum[2]  = {};

    // issue one 64-key iteration (2 sub-tiles of K and V) into buffer it&1
    auto issue = [&](int it) {
        u16* kb = Ks + (it&1)*4096;
        u16* vb = Vt + (it&1)*4096;
        const u16* sk = srcK + (size_t)it*64*DHEAD;
        const u16* sv = srcV + it*64;
        __builtin_amdgcn_global_load_lds(
            (__attribute__((address_space(1))) void*)(sk),
            (__attribute__((address_space(3))) void*)(kb + tid*8), 16, 0, 0);
        __builtin_amdgcn_global_load_lds(
            (__attribute__((address_space(1))) void*)(sk + 32*DHEAD),
            (__attribute__((address_space(3))) void*)(kb + 2048 + tid*8), 16, 0, 0);
        __builtin_amdgcn_global_load_lds(
            (__attribute__((address_space(1))) void*)(sv),
            (__attribute__((address_space(3))) void*)(vb + tid*8), 16, 0, 0);
        __builtin_amdgcn_global_load_lds(
            (__attribute__((address_space(1))) void*)(sv + 32),
            (__attribute__((address_space(3))) void*)(vb + 2048 + tid*8), 16, 0, 0);
    };

    // one proven 32-key sub-body (r3/r4 offsets & math)
    auto sub = [&](const u16* Kb, const u16* Vb) {
        V8 vt[4];
#pragma unroll
        for (int dt = 0; dt < 4; ++dt) {
            vt[dt].h[0] = *(const s16x4*)(const void*)(Vb + dt*512 + vo0);
            vt[dt].h[1] = *(const s16x4*)(const void*)(Vb + dt*512 + vo1);
        }
        B8 pb[2];
#pragma unroll
        for (int mt = 0; mt < 2; ++mt) {
            bf16x8 kf0 = *(const bf16x8*)(const void*)(Kb + mt*1024 + ko0);
            bf16x8 kf1 = *(const bf16x8*)(const void*)(Kb + mt*1024 + ko1);
            f32x4 s[2] = {};
            __builtin_amdgcn_s_setprio(1);
#pragma unroll
            for (int nt = 0; nt < 2; ++nt)
                s[nt] = __builtin_amdgcn_mfma_f32_16x16x32_bf16(kf0, qb[nt][0], s[nt], 0, 0, 0);
#pragma unroll
            for (int nt = 0; nt < 2; ++nt)
                s[nt] = __builtin_amdgcn_mfma_f32_16x16x32_bf16(kf1, qb[nt][1], s[nt], 0, 0, 0);
            __builtin_amdgcn_s_setprio(0);
#pragma unroll
            for (int nt = 0; nt < 2; ++nt) {
                float p0 = __builtin_amdgcn_exp2f(s[nt][0]);
                float p1 = __builtin_amdgcn_exp2f(s[nt][1]);
                float p2 = __builtin_amdgcn_exp2f(s[nt][2]);
                float p3 = __builtin_amdgcn_exp2f(s[nt][3]);
                pb[nt].w[2*mt]   = pkbf(p0, p1);
                pb[nt].w[2*mt+1] = pkbf(p2, p3);
            }
        }
        __builtin_amdgcn_s_setprio(1);
#pragma unroll
        for (int nt = 0; nt < 2; ++nt)
            lsum[nt] = __builtin_amdgcn_mfma_f32_16x16x32_bf16(ones, pb[nt].f, lsum[nt], 0, 0, 0);
#pragma unroll
        for (int dt = 0; dt < 4; ++dt)
#pragma unroll
            for (int nt = 0; nt < 2; ++nt)
                ot[dt][nt] = __builtin_amdgcn_mfma_f32_16x16x32_bf16(vt[dt].f, pb[nt].f, ot[dt][nt], 0, 0, 0);
        __builtin_amdgcn_s_setprio(0);
    };

    // prologue
    issue(0);

    for (int it = 0; it < SS/64; ++it) {
        // wait for this iteration's 4 DMAs (they had a full iteration to land), all ds_reads done
        asm volatile("s_waitcnt vmcnt(0) lgkmcnt(0)\n\ts_barrier" ::: "memory");
        if (it < SS/64 - 1) issue(it + 1);   // prefetch next into the other buffer
        const u16* Kb = Ks + (it&1)*4096;
        const u16* Vb = Vt + (it&1)*4096;
        sub(Kb, Vb);                 // keys it*64 .. +32
        sub(Kb + 2048, Vb + 2048);   // keys it*64+32 .. +64
    }

    // epilogue: O = O^T / lsum (lsum complete per lane), packed 8B stores
    float inv[2];
#pragma unroll
    for (int nt = 0; nt < 2; ++nt) inv[nt] = 1.0f / lsum[nt][0];
#pragma unroll
    for (int dt = 0; dt < 4; ++dt)
#pragma unroll
        for (int nt = 0; nt < 2; ++nt) {
            u64 w = (u64)pkbf(ot[dt][nt][0]*inv[nt], ot[dt][nt][1]*inv[nt])
                  | ((u64)pkbf(ot[dt][nt][2]*inv[nt], ot[dt][nt][3]*inv[nt]) << 32);
            *(u64*)(outb + ((size_t)(b*SS + qbase + nt*16 + l16))*D_MODEL
                         + h*64 + dt*16 + quad*4) = w;
        }
}

// ---------------------------------------------------------------- launcher
extern "C" void kernel_launch(void* const* d_in, const int* in_sizes, int n_in,
                              void* d_out, int out_size, void* d_ws, size_t ws_size,
                              hipStream_t stream)
{
    (void)in_sizes; (void)n_in; (void)out_size; (void)ws_size;
    const float* x  = (const float*)d_in[0];
    const float* wq = (const float*)d_in[1];
    const float* wo = (const float*)d_in[2];
    const float* bo = (const float*)d_in[3];

    char* ws = (char*)d_ws;
    u16* xb    = (u16*)(ws);                          // 16 MiB  [8192][1024] bf16 x
    u16* wqb   = (u16*)(ws + (size_t)(16 << 20));     //  2 MiB
    u16* wob   = (u16*)(ws + (size_t)(18 << 20));     //  2 MiB
    u16* qkvb  = (u16*)(ws + (size_t)(20 << 20));     // 16 MiB  [64][2048][64]
    u16* qkvTb = (u16*)(ws + (size_t)(36 << 20));     // 16 MiB  [64][64][2048]
    u16* attb  = xb;                                  // reuse x-bf16 buffer for attention output

    cvt_all_kernel<<<(N4X + 2*N4W) / 256, 256, 0, stream>>>(x, wq, wo, xb, wqb, wob);
    gemm_qkv_kernel<<<(MM/128) * (D_MODEL/128), 256, 0, stream>>>(xb, wqb, qkvb, qkvTb);
    attn_kernel<<<BB * NH * (SS/128), 256, 0, stream>>>(qkvb, qkvTb, attb);
    gemm_out_kernel<<<(MM/128) * (D_MODEL/128), 256, 0, stream>>>(attb, wob, bo, (float*)d_out);
}